// Round 1
// baseline (43589.236 us; speedup 1.0000x reference)
//
#include <hip/hip_runtime.h>
#include <cstdint>
#include <cstddef>

// ---------------------------------------------------------------------------
// BaseDecoder: 128-step LSTM decoder with jax.random.categorical sampling.
//
// Structure per call (all on `stream`, graph-capture safe):
//   k_init                      : features mean-pool, x init (emb[1]), zero h/c,
//                                 zero winners/counters (ws is poisoned each call)
//   128 x { k_lstm, k_logits }  : LSTM step (z = x@K + h@R + b, cell update),
//                                 logits + gumbel + argmax + embed gather
//
// v2 data path: activation broadcasts moved off the scalar pipe.
//   Activations (x rows / h rows) are staged into LDS per pass via
//   global_load_lds (16B/lane, linear dest), double-buffered; the FMA loop
//   reads them with wave-uniform ds_read_b128 (broadcast, conflict-free).
//   Weights are prefetched 16-deep (logits) / 7-deep (lstm) per pass.
//
// PRNG: JAX threefry, *partitionable* variant (default since jax 0.5):
//   split(key)  -> row_i = threefry(key, (0, i)) (both words)
//   bits(i)     = w0 ^ w1 of threefry(subkey, (0, i)), i = b*32000 + v
//   uniform     = bitcast((bits>>9)|0x3f800000) - 1, max(tiny, . + tiny)
//   gumbel      = -log(-log(u)); sample = argmax(logits + gumbel), first index
// Key chain computed on host (pure, same every call) and passed as args.
//
// ws layout (needs ~4.75 MB):
//   [0       ) winners  128*32 u64      (packed argmax, atomicMax)
//   [32768   ) cntA     128*16 u32      (lstm split-k group counters)
//   [40960   ) cntB     128    u32      (logits block counters)
//   [49152   ) xT       768*32 f32      (x transposed [row][batch]; rows 0-255
//                                        emb[sample], 256-767 features)
//   [147456  ) hb0      1024*32 f32     (h ping)
//   [278528  ) hb1      1024*32 f32     (h pong)
//   [409600  ) cT       1024*32 f32     (cell state [u][b])
//   [540672  ) zpart    8*4096*32 f32   (split-k partials of z)
// ---------------------------------------------------------------------------

#define VOCAB 32000
#define EMB 256
#define UNITS 1024
#define STEPS 128
#define BATCH 32
#define XROWS 768
#define TINYF 1.17549435e-38f

// Threefry-2x32, 20 rounds (matches jax._src.prng exactly).
__host__ __device__ __forceinline__ void tf2x32(uint32_t k0, uint32_t k1,
                                                uint32_t x0, uint32_t x1,
                                                uint32_t& o0, uint32_t& o1) {
  uint32_t ks2 = k0 ^ k1 ^ 0x1BD11BDAu;
#define TFR(r) { x0 += x1; x1 = (x1 << (r)) | (x1 >> (32 - (r))); x1 ^= x0; }
  x0 += k0; x1 += k1;
  TFR(13) TFR(15) TFR(26) TFR(6)  x0 += k1;  x1 += ks2 + 1u;
  TFR(17) TFR(29) TFR(16) TFR(24) x0 += ks2; x1 += k0 + 2u;
  TFR(13) TFR(15) TFR(26) TFR(6)  x0 += k0;  x1 += k1 + 3u;
  TFR(17) TFR(29) TFR(16) TFR(24) x0 += k1;  x1 += ks2 + 4u;
  TFR(13) TFR(15) TFR(26) TFR(6)  x0 += ks2; x1 += k0 + 5u;
#undef TFR
  o0 = x0; o1 = x1;
}

// global->LDS direct copy, 16 B per lane. LDS dest is wave-uniform base +
// lane*16 (linear rule); global source address is per-lane.
__device__ __forceinline__ void gld_lds16(const float* g, float* l) {
  __builtin_amdgcn_global_load_lds(
      (const __attribute__((address_space(1))) void*)(g),
      (__attribute__((address_space(3))) void*)(l), 16, 0, 0);
}

// ---------------------------------------------------------------------------
__global__ __launch_bounds__(256) void k_init(
    const float* __restrict__ img, const float* __restrict__ emb,
    float* __restrict__ xT, float* __restrict__ h0, float* __restrict__ cT,
    unsigned long long* __restrict__ winners, unsigned int* __restrict__ cntA,
    unsigned int* __restrict__ cntB) {
  int idx = blockIdx.x * 256 + threadIdx.x;
  if (idx < 16384) {                       // features: mean over 200 positions
    int b = idx >> 9, ch = idx & 511;
    const float* p = img + (size_t)b * 102400 + ch;
    float s = 0.f;
    for (int t = 0; t < 200; ++t) s += p[(size_t)t * 512];
    xT[(size_t)(256 + ch) * 32 + b] = s / 200.0f;
  } else if (idx < 24576) {                // start token embedding (row 1)
    int i2 = idx - 16384;
    int e = i2 >> 5, b = i2 & 31;
    xT[(size_t)e * 32 + b] = emb[256 + e];
  } else if (idx < 57344) {
    h0[idx - 24576] = 0.f;
  } else if (idx < 90112) {
    cT[idx - 57344] = 0.f;
  } else if (idx < 94208) {
    winners[idx - 90112] = 0ull;
  } else if (idx < 96256) {
    cntA[idx - 94208] = 0u;
  } else if (idx < 96384) {
    cntB[idx - 96256] = 0u;
  }
}

// ---------------------------------------------------------------------------
// LSTM step. Grid 512 = 64 column-tiles (64 of 4096 z cols) x 8 k-eighths.
// Block 512 = 8 wave-strips x 64 lanes(columns). Each block covers 224 k-rows
// (e*224..), processed in 4 LDS passes of 56 rows; strip s handles local rows
// [s*7, s*7+7) of each pass. Last block of each group of 32 (same hidden-unit
// tile) performs the cell update into cT / hw.
__global__ __launch_bounds__(512, 4) void k_lstm(
    const float* __restrict__ Km, const float* __restrict__ Rm,
    const float* __restrict__ bias, const float* __restrict__ xT,
    const float* __restrict__ hr, float* __restrict__ hw,
    float* __restrict__ cT, float* __restrict__ zpart,
    unsigned int* cntA, int t) {
  const int tid = threadIdx.x;
  const int lane = tid & 63;
  const int strip = __builtin_amdgcn_readfirstlane(tid >> 6);
  const int jt = blockIdx.x >> 3;
  const int e = blockIdx.x & 7;
  const int j = jt * 64 + lane;
  const int m = jt & 15;
  const int R0 = e * 224;

  __shared__ float xs[2][56][32];   // double-buffered activation rows
  __shared__ float red[4][64][33];
  __shared__ int lastf;

  float acc[32];
#pragma unroll
  for (int b = 0; b < 32; ++b) acc[b] = 0.f;

  // Stage pass 0 (rows R0..R0+55, 7 KB = 448 slots of 16 B; waves 0-6).
  if (strip < 7) {
    const int slot = strip * 64 + lane;
    const int row = slot >> 3, c4 = (slot & 7) * 4;
    const int g = R0 + row;
    const float* src = (g < XROWS) ? (xT + (size_t)g * 32 + c4)
                                   : (hr + (size_t)(g - XROWS) * 32 + c4);
    gld_lds16(src, &xs[0][0][0] + strip * 256);
  }

  for (int p = 0; p < 4; ++p) {
    // __syncthreads emits s_waitcnt vmcnt(0) lgkmcnt(0) before s_barrier:
    // drains this wave's stage loads, then publishes the buffer.
    __syncthreads();
    if (p < 3 && strip < 7) {       // issue next pass's stage (overlaps FMAs)
      const int slot = strip * 64 + lane;
      const int row = slot >> 3, c4 = (slot & 7) * 4;
      const int g = R0 + (p + 1) * 56 + row;
      const float* src = (g < XROWS) ? (xT + (size_t)g * 32 + c4)
                                     : (hr + (size_t)(g - XROWS) * 32 + c4);
      gld_lds16(src, &xs[(p + 1) & 1][0][0] + strip * 256);
    }
    float w[7];                     // 7 weight loads in flight per pass
#pragma unroll
    for (int i = 0; i < 7; ++i) {
      const int g = R0 + p * 56 + strip * 7 + i;
      w[i] = (g < XROWS) ? Km[(size_t)g * 4096 + j]
                         : Rm[(size_t)(g - XROWS) * 4096 + j];
    }
    const int buf = p & 1;
#pragma unroll
    for (int i = 0; i < 7; ++i) {
      const float4* xr =
          reinterpret_cast<const float4*>(&xs[buf][strip * 7 + i][0]);
      float4 xv[8];
#pragma unroll
      for (int c = 0; c < 8; ++c) xv[c] = xr[c];  // ds_read_b128, broadcast
#pragma unroll
      for (int c = 0; c < 8; ++c) {
        acc[4 * c + 0] = fmaf(w[i], xv[c].x, acc[4 * c + 0]);
        acc[4 * c + 1] = fmaf(w[i], xv[c].y, acc[4 * c + 1]);
        acc[4 * c + 2] = fmaf(w[i], xv[c].z, acc[4 * c + 2]);
        acc[4 * c + 3] = fmaf(w[i], xv[c].w, acc[4 * c + 3]);
      }
    }
  }

  if (strip < 4) {
#pragma unroll
    for (int b = 0; b < 32; ++b) red[strip][lane][b] = acc[b];
  }
  __syncthreads();
  if (strip >= 4) {
#pragma unroll
    for (int b = 0; b < 32; ++b) red[strip - 4][lane][b] += acc[b];
  }
  __syncthreads();

#pragma unroll
  for (int it = 0; it < 4; ++it) {
    int idx = it * 512 + tid;
    int col = idx >> 5, b = idx & 31;
    float s = ((red[0][col][b] + red[1][col][b]) + red[2][col][b]) +
              red[3][col][b];
    zpart[((size_t)e * 4096 + jt * 64 + col) * 32 + b] = s;
  }
  __syncthreads();
  if (tid == 0) {
    __threadfence();
    unsigned int old = atomicAdd(&cntA[t * 16 + m], 1u);
    lastf = (old == 31u);
  }
  __syncthreads();

  if (lastf) {
    __threadfence();
#pragma unroll
    for (int it = 0; it < 4; ++it) {
      int idx = it * 512 + tid;
      int ul = idx >> 5, b = idx & 31;
      int u = m * 64 + ul;
      float zs[4];
#pragma unroll
      for (int g = 0; g < 4; ++g) {
        int jj = g * 1024 + u;
        const float* zp = zpart + (size_t)jj * 32 + b;
        float s = zp[0];
#pragma unroll
        for (int ee = 1; ee < 8; ++ee) s += zp[(size_t)ee * 4096 * 32];
        zs[g] = s + bias[jj];
      }
      float ig = 1.0f / (1.0f + expf(-zs[0]));
      float fg = 1.0f / (1.0f + expf(-zs[1]));
      float og = 1.0f / (1.0f + expf(-zs[3]));
      float cold = cT[(size_t)u * 32 + b];
      float cn = fg * cold + ig * tanhf(zs[2]);
      cT[(size_t)u * 32 + b] = cn;
      hw[(size_t)u * 32 + b] = og * tanhf(cn);
    }
  }
}

// ---------------------------------------------------------------------------
// Logits + gumbel + argmax + sample + embedding gather.
// Grid 500 (64 vocab cols each) x block 512 (8 wave-strips). h (1024 rows) is
// processed in 8 LDS passes of 128 rows; strip s handles local rows
// [s*16, s*16+16) of each pass. xs is unioned with the post-loop reduction
// arrays to stay under the 64 KB static-LDS limit (alias boundary = the
// __syncthreads after the main loop).
__global__ __launch_bounds__(512, 4) void k_logits(
    const float* __restrict__ Pw, const float* __restrict__ pb,
    const float* __restrict__ emb, const float* __restrict__ hr,
    float* __restrict__ xT, unsigned long long* winners,
    unsigned int* cntB, int* __restrict__ out, int t, uint32_t s0,
    uint32_t s1) {
  const int tid = threadIdx.x;
  const int lane = tid & 63;
  const int strip = __builtin_amdgcn_readfirstlane(tid >> 6);
  const int v0 = blockIdx.x * 64;

  __shared__ union {
    float xs[2][128][32];           // 32 KB, live during the FMA loop only
    struct {
      float red[4][64][33];
      unsigned long long wbs[32][17];
      int samp[BATCH];
    } r;                            // 38.3 KB, live after the FMA loop only
  } sh;
  __shared__ int lastf;

  float acc[32];
#pragma unroll
  for (int b = 0; b < 32; ++b) acc[b] = 0.f;

  // Stage pass 0: h rows 0..127 (16 KB), 2 chunks of 1 KB per wave.
  {
    const int c0 = strip * 2;
    gld_lds16(hr + (size_t)c0 * 256 + lane * 4, &sh.xs[0][0][0] + c0 * 256);
    gld_lds16(hr + (size_t)(c0 + 1) * 256 + lane * 4,
              &sh.xs[0][0][0] + (c0 + 1) * 256);
  }

  for (int p = 0; p < 8; ++p) {
    __syncthreads();                // drain stage p (vmcnt 0) + publish
    if (p < 7) {                    // issue stage p+1, hides under FMAs
      const int c0 = strip * 2;
      const float* src = hr + (size_t)(p + 1) * 4096;
      float* dst = &sh.xs[(p + 1) & 1][0][0];
      gld_lds16(src + (size_t)c0 * 256 + lane * 4, dst + c0 * 256);
      gld_lds16(src + (size_t)(c0 + 1) * 256 + lane * 4, dst + (c0 + 1) * 256);
    }
    const float* wp = Pw + (size_t)(p * 128 + strip * 16) * VOCAB + v0 + lane;
    float w[16];                    // 16 weight loads in flight per pass
#pragma unroll
    for (int i = 0; i < 16; ++i) w[i] = wp[(size_t)i * VOCAB];
    const int buf = p & 1;
#pragma unroll
    for (int i = 0; i < 16; ++i) {
      const float4* xr =
          reinterpret_cast<const float4*>(&sh.xs[buf][strip * 16 + i][0]);
      float4 xv[8];
#pragma unroll
      for (int c = 0; c < 8; ++c) xv[c] = xr[c];  // ds_read_b128, broadcast
#pragma unroll
      for (int c = 0; c < 8; ++c) {
        acc[4 * c + 0] = fmaf(w[i], xv[c].x, acc[4 * c + 0]);
        acc[4 * c + 1] = fmaf(w[i], xv[c].y, acc[4 * c + 1]);
        acc[4 * c + 2] = fmaf(w[i], xv[c].z, acc[4 * c + 2]);
        acc[4 * c + 3] = fmaf(w[i], xv[c].w, acc[4 * c + 3]);
      }
    }
  }

  __syncthreads();                  // alias boundary: all xs reads complete

  if (strip < 4) {
#pragma unroll
    for (int b = 0; b < 32; ++b) sh.r.red[strip][lane][b] = acc[b];
  }
  __syncthreads();
  if (strip >= 4) {
#pragma unroll
    for (int b = 0; b < 32; ++b) sh.r.red[strip - 4][lane][b] += acc[b];
  }
  __syncthreads();

#pragma unroll
  for (int it = 0; it < 4; ++it) {
    int idx = it * 512 + tid;
    int col = idx >> 5, b = idx & 31;
    float s = ((sh.r.red[0][col][b] + sh.r.red[1][col][b]) +
               sh.r.red[2][col][b]) +
              sh.r.red[3][col][b] + pb[v0 + col];
    sh.r.red[0][col][b] = s;
  }
  __syncthreads();

  {
    const int b = tid & 31;
    const int sub = tid >> 5;
    unsigned long long best = 0ull;
#pragma unroll
    for (int c = 0; c < 4; ++c) {
      int col = sub * 4 + c;
      int vv = v0 + col;
      float logit = sh.r.red[0][col][b];
      uint32_t y0, y1;
      tf2x32(s0, s1, 0u, (uint32_t)(b * VOCAB + vv), y0, y1);
      uint32_t bits = y0 ^ y1;  // jax partitionable 32-bit random_bits
      uint32_t fb = (bits >> 9) | 0x3F800000u;
      float f = __uint_as_float(fb) - 1.0f;
      float u = f + TINYF;
      u = fmaxf(TINYF, u);
      float g = -logf(-logf(u));
      float val = g + logit;
      uint32_t ub = __float_as_uint(val);
      ub = ((int)ub < 0) ? ~ub : (ub | 0x80000000u);
      unsigned long long pk =
          ((unsigned long long)ub << 32) | (uint32_t)(~(uint32_t)vv);
      if (pk > best) best = pk;
    }
    sh.r.wbs[b][sub] = best;
  }
  __syncthreads();

  if (tid < 32) {
    unsigned long long best = sh.r.wbs[tid][0];
#pragma unroll
    for (int s = 1; s < 16; ++s)
      best = (sh.r.wbs[tid][s] > best) ? sh.r.wbs[tid][s] : best;
    unsigned long long cur = winners[t * 32 + tid];  // stale-ok prune read
    if (best > cur) atomicMax(&winners[t * 32 + tid], best);
  }
  __syncthreads();
  if (tid == 0) {
    __threadfence();
    unsigned int old = atomicAdd(&cntB[t], 1u);
    lastf = (old == 499u);
  }
  __syncthreads();

  if (lastf) {
    __threadfence();
    if (tid < 32) {
      unsigned long long w = atomicMax(&winners[t * 32 + tid], 0ull);
      int vv = (int)(~(uint32_t)(w & 0xFFFFFFFFull));
      sh.r.samp[tid] = vv;
      out[tid * STEPS + t] = vv;
    }
    __syncthreads();
#pragma unroll
    for (int it = 0; it < 16; ++it) {
      int idx = it * 512 + tid;
      int b = idx >> 8, e2 = idx & 255;
      xT[(size_t)e2 * 32 + b] = emb[(size_t)sh.r.samp[b] * EMB + e2];
    }
  }
}

// ---------------------------------------------------------------------------
extern "C" void kernel_launch(void* const* d_in, const int* in_sizes, int n_in,
                              void* d_out, int out_size, void* d_ws,
                              size_t ws_size, hipStream_t stream) {
  (void)in_sizes; (void)n_in; (void)out_size; (void)ws_size;
  const float* img  = (const float*)d_in[0];
  const float* emb  = (const float*)d_in[1];
  const float* Km   = (const float*)d_in[2];
  const float* Rm   = (const float*)d_in[3];
  const float* bias = (const float*)d_in[4];
  const float* Pw   = (const float*)d_in[5];
  const float* pb   = (const float*)d_in[6];
  int* out = (int*)d_out;

  char* ws = (char*)d_ws;
  unsigned long long* winners = (unsigned long long*)(ws + 0);
  unsigned int* cntA = (unsigned int*)(ws + 32768);
  unsigned int* cntB = (unsigned int*)(ws + 40960);
  float* xT   = (float*)(ws + 49152);
  float* hb0  = (float*)(ws + 147456);
  float* hb1  = (float*)(ws + 278528);
  float* cT   = (float*)(ws + 409600);
  float* zpart = (float*)(ws + 540672);

  k_init<<<377, 256, 0, stream>>>(img, emb, xT, hb0, cT, winners, cntA, cntB);

  // Host-side key chain (pure, identical every call -> graph-capture safe).
  uint32_t k0 = 0u, k1 = 42u;  // jax.random.key(42) -> [0, 42]
  for (int t = 0; t < STEPS; ++t) {
    uint32_t n0, n1, su0, su1;
    tf2x32(k0, k1, 0u, 0u, n0, n1);   // split row 0 -> new key
    tf2x32(k0, k1, 0u, 1u, su0, su1); // split row 1 -> subkey
    k0 = n0; k1 = n1;

    const float* hrd = (t & 1) ? hb1 : hb0;
    float* hwr = (t & 1) ? hb0 : hb1;
    k_lstm<<<512, 512, 0, stream>>>(Km, Rm, bias, xT, hrd, hwr, cT, zpart,
                                    cntA, t);
    k_logits<<<500, 512, 0, stream>>>(Pw, pb, emb, hwr, xT, winners, cntB,
                                      out, t, su0, su1);
  }
}

// Round 2
// 11217.332 us; speedup vs baseline: 3.8859x; 3.8859x over previous
//
#include <hip/hip_runtime.h>
#include <cstdint>
#include <cstddef>

// ---------------------------------------------------------------------------
// BaseDecoder: 128-step LSTM decoder with jax.random.categorical sampling.
//
// Structure per call (all on `stream`, graph-capture safe):
//   k_init                      : features mean-pool, x init (emb[1]), zero h/c,
//                                 zero winners/counters (ws is poisoned each call)
//   128 x { k_lstm, k_logits }  : LSTM step (z = x@K + h@R + b, cell update),
//                                 logits + gumbel + argmax + embed gather
//
// v3: baseline structure (12.8 ms) with the scalar broadcast path paired:
//   one s_waitcnt lgkmcnt(0) now covers TWO activation rows (4x
//   s_load_dwordx16 from one base), halving the number of exposed
//   scalar-fetch stalls in both hot loops.
//
// PRNG: JAX threefry, *partitionable* variant (default since jax 0.5):
//   split(key)  -> row_i = threefry(key, (0, i)) (both words)
//   bits(i)     = w0 ^ w1 of threefry(subkey, (0, i)), i = b*32000 + v
//   uniform     = bitcast((bits>>9)|0x3f800000) - 1, max(tiny, . + tiny)
//   gumbel      = -log(-log(u)); sample = argmax(logits + gumbel), first index
// Key chain computed on host (pure, same every call) and passed as args.
//
// ws layout (needs ~4.75 MB):
//   [0       ) winners  128*32 u64      (packed argmax, atomicMax)
//   [32768   ) cntA     128*16 u32      (lstm split-k group counters)
//   [40960   ) cntB     128    u32      (logits block counters)
//   [49152   ) xT       768*32 f32      (x transposed [row][batch]; rows 0-255
//                                        emb[sample], 256-767 features)
//   [147456  ) hb0      1024*32 f32     (h ping)
//   [278528  ) hb1      1024*32 f32     (h pong)
//   [409600  ) cT       1024*32 f32     (cell state [u][b])
//   [540672  ) zpart    8*4096*32 f32   (split-k partials of z)
// ---------------------------------------------------------------------------

#define VOCAB 32000
#define EMB 256
#define UNITS 1024
#define STEPS 128
#define BATCH 32
#define XROWS 768
#define TINYF 1.17549435e-38f

typedef uint32_t u32x16 __attribute__((ext_vector_type(16)));

// Threefry-2x32, 20 rounds (matches jax._src.prng exactly).
__host__ __device__ __forceinline__ void tf2x32(uint32_t k0, uint32_t k1,
                                                uint32_t x0, uint32_t x1,
                                                uint32_t& o0, uint32_t& o1) {
  uint32_t ks2 = k0 ^ k1 ^ 0x1BD11BDAu;
#define TFR(r) { x0 += x1; x1 = (x1 << (r)) | (x1 >> (32 - (r))); x1 ^= x0; }
  x0 += k0; x1 += k1;
  TFR(13) TFR(15) TFR(26) TFR(6)  x0 += k1;  x1 += ks2 + 1u;
  TFR(17) TFR(29) TFR(16) TFR(24) x0 += ks2; x1 += k0 + 2u;
  TFR(13) TFR(15) TFR(26) TFR(6)  x0 += k0;  x1 += k1 + 3u;
  TFR(17) TFR(29) TFR(16) TFR(24) x0 += k1;  x1 += ks2 + 4u;
  TFR(13) TFR(15) TFR(26) TFR(6)  x0 += ks2; x1 += k0 + 5u;
#undef TFR
  o0 = x0; o1 = x1;
}

// Wave-uniform broadcast load of TWO consecutive activation rows (64 floats,
// rows are 128 B apart and contiguous) through the scalar path:
// 4x s_load_dwordx16 + ONE lgkmcnt(0) drain. p MUST be wave-uniform.
__device__ __forceinline__ void sload2_b(const float* p, u32x16& a, u32x16& b,
                                         u32x16& c, u32x16& d) {
  asm volatile("s_load_dwordx16 %0, %4, 0x0\n\t"
               "s_load_dwordx16 %1, %4, 0x40\n\t"
               "s_load_dwordx16 %2, %4, 0x80\n\t"
               "s_load_dwordx16 %3, %4, 0xc0\n\t"
               "s_waitcnt lgkmcnt(0)"
               : "=&s"(a), "=&s"(b), "=&s"(c), "=&s"(d)
               : "s"(p));
}

__device__ __forceinline__ void fma32(float* acc, float w,
                                      const u32x16& xa, const u32x16& xb) {
#pragma unroll
  for (int b = 0; b < 16; ++b)
    acc[b] = fmaf(w, __uint_as_float(xa[b]), acc[b]);
#pragma unroll
  for (int b = 0; b < 16; ++b)
    acc[b + 16] = fmaf(w, __uint_as_float(xb[b]), acc[b + 16]);
}

// ---------------------------------------------------------------------------
__global__ __launch_bounds__(256) void k_init(
    const float* __restrict__ img, const float* __restrict__ emb,
    float* __restrict__ xT, float* __restrict__ h0, float* __restrict__ cT,
    unsigned long long* __restrict__ winners, unsigned int* __restrict__ cntA,
    unsigned int* __restrict__ cntB) {
  int idx = blockIdx.x * 256 + threadIdx.x;
  if (idx < 16384) {                       // features: mean over 200 positions
    int b = idx >> 9, ch = idx & 511;
    const float* p = img + (size_t)b * 102400 + ch;
    float s = 0.f;
    for (int t = 0; t < 200; ++t) s += p[(size_t)t * 512];
    xT[(size_t)(256 + ch) * 32 + b] = s / 200.0f;
  } else if (idx < 24576) {                // start token embedding (row 1)
    int i2 = idx - 16384;
    int e = i2 >> 5, b = i2 & 31;
    xT[(size_t)e * 32 + b] = emb[256 + e];
  } else if (idx < 57344) {
    h0[idx - 24576] = 0.f;
  } else if (idx < 90112) {
    cT[idx - 57344] = 0.f;
  } else if (idx < 94208) {
    winners[idx - 90112] = 0ull;
  } else if (idx < 96256) {
    cntA[idx - 94208] = 0u;
  } else if (idx < 96384) {
    cntB[idx - 96256] = 0u;
  }
}

// ---------------------------------------------------------------------------
// LSTM step. Grid 512 = 64 column-tiles (64 of 4096 z cols) x 8 k-eighths.
// Block 512 = 8 wave-strips x 64 lanes(columns). Last block of each group of
// 32 (same hidden-unit tile) performs the cell update into cT / hw.
// k range per strip is 28 rows = 14 pairs; pairs never straddle the xT->hr
// boundary (row 768) because klo and 768 are both even.
__global__ __launch_bounds__(512) void k_lstm(
    const float* __restrict__ Km, const float* __restrict__ Rm,
    const float* __restrict__ bias, const float* __restrict__ xT,
    const float* __restrict__ hr, float* __restrict__ hw,
    float* __restrict__ cT, float* __restrict__ zpart,
    unsigned int* cntA, int t) {
  const int tid = threadIdx.x;
  const int lane = tid & 63;
  const int strip = __builtin_amdgcn_readfirstlane(tid >> 6);
  const int jt = blockIdx.x >> 3;
  const int e = blockIdx.x & 7;
  const int j = jt * 64 + lane;
  const int m = jt & 15;

  __shared__ float red[4][64][33];
  __shared__ int lastf;

  float acc[32];
#pragma unroll
  for (int b = 0; b < 32; ++b) acc[b] = 0.f;

  const int klo = e * 224 + strip * 28;
  const int khi = klo + 28;

#define WROW(g) ((g) < XROWS ? Km[(size_t)(g) * 4096 + j] \
                             : Rm[(size_t)((g) - XROWS) * 4096 + j])
  float wc0 = WROW(klo);
  float wc1 = WROW(klo + 1);
  for (int k = klo; k < khi; k += 2) {
    float wn0 = 0.f, wn1 = 0.f;
    if (k + 2 < khi) { wn0 = WROW(k + 2); wn1 = WROW(k + 3); }
    const float* xrow = (k < XROWS) ? (xT + (size_t)k * 32)
                                    : (hr + (size_t)(k - XROWS) * 32);
    u32x16 xa, xb, xc, xd;
    sload2_b(xrow, xa, xb, xc, xd);
    fma32(acc, wc0, xa, xb);
    fma32(acc, wc1, xc, xd);
    wc0 = wn0; wc1 = wn1;
  }
#undef WROW

  if (strip < 4) {
#pragma unroll
    for (int b = 0; b < 32; ++b) red[strip][lane][b] = acc[b];
  }
  __syncthreads();
  if (strip >= 4) {
#pragma unroll
    for (int b = 0; b < 32; ++b) red[strip - 4][lane][b] += acc[b];
  }
  __syncthreads();

#pragma unroll
  for (int it = 0; it < 4; ++it) {
    int idx = it * 512 + tid;
    int col = idx >> 5, b = idx & 31;
    float s = ((red[0][col][b] + red[1][col][b]) + red[2][col][b]) +
              red[3][col][b];
    zpart[((size_t)e * 4096 + jt * 64 + col) * 32 + b] = s;
  }
  __syncthreads();
  if (tid == 0) {
    __threadfence();
    unsigned int old = atomicAdd(&cntA[t * 16 + m], 1u);
    lastf = (old == 31u);
  }
  __syncthreads();

  if (lastf) {
    __threadfence();
#pragma unroll
    for (int it = 0; it < 4; ++it) {
      int idx = it * 512 + tid;
      int ul = idx >> 5, b = idx & 31;
      int u = m * 64 + ul;
      float zs[4];
#pragma unroll
      for (int g = 0; g < 4; ++g) {
        int jj = g * 1024 + u;
        const float* zp = zpart + (size_t)jj * 32 + b;
        float s = zp[0];
#pragma unroll
        for (int ee = 1; ee < 8; ++ee) s += zp[(size_t)ee * 4096 * 32];
        zs[g] = s + bias[jj];
      }
      float ig = 1.0f / (1.0f + expf(-zs[0]));
      float fg = 1.0f / (1.0f + expf(-zs[1]));
      float og = 1.0f / (1.0f + expf(-zs[3]));
      float cold = cT[(size_t)u * 32 + b];
      float cn = fg * cold + ig * tanhf(zs[2]);
      cT[(size_t)u * 32 + b] = cn;
      hw[(size_t)u * 32 + b] = og * tanhf(cn);
    }
  }
}

// ---------------------------------------------------------------------------
// Logits + gumbel + argmax + sample + embedding gather.
// Grid 500 (64 vocab cols each) x block 512 (8 wave-strips of 128 h-units).
// h rows per strip are contiguous, consumed as 64 pairs (one lgkm drain each).
__global__ __launch_bounds__(512) void k_logits(
    const float* __restrict__ Pw, const float* __restrict__ pb,
    const float* __restrict__ emb, const float* __restrict__ hr,
    float* __restrict__ xT, unsigned long long* winners,
    unsigned int* cntB, int* __restrict__ out, int t, uint32_t s0,
    uint32_t s1) {
  const int tid = threadIdx.x;
  const int lane = tid & 63;
  const int strip = __builtin_amdgcn_readfirstlane(tid >> 6);
  const int v0 = blockIdx.x * 64;

  __shared__ float red[4][64][33];
  __shared__ unsigned long long wbs[32][17];
  __shared__ int samp[BATCH];
  __shared__ int lastf;

  float acc[32];
#pragma unroll
  for (int b = 0; b < 32; ++b) acc[b] = 0.f;

  {
    const float* xp = hr + (size_t)(strip * 128) * 32;
    const float* wp = Pw + (size_t)(strip * 128) * VOCAB + v0 + lane;
    float wc0 = wp[0], wc1 = wp[VOCAB], wc2 = wp[2 * VOCAB],
          wc3 = wp[3 * VOCAB];
    const float* wpp = wp + (size_t)4 * VOCAB;
    u32x16 xa, xb, xc, xd;
    for (int k = 0; k < 124; k += 4) {
      float wn0 = wpp[0], wn1 = wpp[VOCAB], wn2 = wpp[2 * VOCAB],
            wn3 = wpp[3 * VOCAB];
      wpp += (size_t)4 * VOCAB;
      sload2_b(xp, xa, xb, xc, xd); xp += 64;
      fma32(acc, wc0, xa, xb);
      fma32(acc, wc1, xc, xd);
      sload2_b(xp, xa, xb, xc, xd); xp += 64;
      fma32(acc, wc2, xa, xb);
      fma32(acc, wc3, xc, xd);
      wc0 = wn0; wc1 = wn1; wc2 = wn2; wc3 = wn3;
    }
    sload2_b(xp, xa, xb, xc, xd); xp += 64;
    fma32(acc, wc0, xa, xb);
    fma32(acc, wc1, xc, xd);
    sload2_b(xp, xa, xb, xc, xd);
    fma32(acc, wc2, xa, xb);
    fma32(acc, wc3, xc, xd);
  }

  if (strip < 4) {
#pragma unroll
    for (int b = 0; b < 32; ++b) red[strip][lane][b] = acc[b];
  }
  __syncthreads();
  if (strip >= 4) {
#pragma unroll
    for (int b = 0; b < 32; ++b) red[strip - 4][lane][b] += acc[b];
  }
  __syncthreads();

#pragma unroll
  for (int it = 0; it < 4; ++it) {
    int idx = it * 512 + tid;
    int col = idx >> 5, b = idx & 31;
    float s = ((red[0][col][b] + red[1][col][b]) + red[2][col][b]) +
              red[3][col][b] + pb[v0 + col];
    red[0][col][b] = s;
  }
  __syncthreads();

  {
    const int b = tid & 31;
    const int sub = tid >> 5;
    unsigned long long best = 0ull;
#pragma unroll
    for (int c = 0; c < 4; ++c) {
      int col = sub * 4 + c;
      int vv = v0 + col;
      float logit = red[0][col][b];
      uint32_t y0, y1;
      tf2x32(s0, s1, 0u, (uint32_t)(b * VOCAB + vv), y0, y1);
      uint32_t bits = y0 ^ y1;  // jax partitionable 32-bit random_bits
      uint32_t fb = (bits >> 9) | 0x3F800000u;
      float f = __uint_as_float(fb) - 1.0f;
      float u = f + TINYF;
      u = fmaxf(TINYF, u);
      float g = -logf(-logf(u));
      float val = g + logit;
      uint32_t ub = __float_as_uint(val);
      ub = ((int)ub < 0) ? ~ub : (ub | 0x80000000u);
      unsigned long long pk =
          ((unsigned long long)ub << 32) | (uint32_t)(~(uint32_t)vv);
      if (pk > best) best = pk;
    }
    wbs[b][sub] = best;
  }
  __syncthreads();

  if (tid < 32) {
    unsigned long long best = wbs[tid][0];
#pragma unroll
    for (int s = 1; s < 16; ++s)
      best = (wbs[tid][s] > best) ? wbs[tid][s] : best;
    unsigned long long cur = winners[t * 32 + tid];  // stale-ok prune read
    if (best > cur) atomicMax(&winners[t * 32 + tid], best);
  }
  __syncthreads();
  if (tid == 0) {
    __threadfence();
    unsigned int old = atomicAdd(&cntB[t], 1u);
    lastf = (old == 499u);
  }
  __syncthreads();

  if (lastf) {
    __threadfence();
    if (tid < 32) {
      unsigned long long w = atomicMax(&winners[t * 32 + tid], 0ull);
      int vv = (int)(~(uint32_t)(w & 0xFFFFFFFFull));
      samp[tid] = vv;
      out[tid * STEPS + t] = vv;
    }
    __syncthreads();
#pragma unroll
    for (int it = 0; it < 16; ++it) {
      int idx = it * 512 + tid;
      int b = idx >> 8, e2 = idx & 255;
      xT[(size_t)e2 * 32 + b] = emb[(size_t)samp[b] * EMB + e2];
    }
  }
}

// ---------------------------------------------------------------------------
extern "C" void kernel_launch(void* const* d_in, const int* in_sizes, int n_in,
                              void* d_out, int out_size, void* d_ws,
                              size_t ws_size, hipStream_t stream) {
  (void)in_sizes; (void)n_in; (void)out_size; (void)ws_size;
  const float* img  = (const float*)d_in[0];
  const float* emb  = (const float*)d_in[1];
  const float* Km   = (const float*)d_in[2];
  const float* Rm   = (const float*)d_in[3];
  const float* bias = (const float*)d_in[4];
  const float* Pw   = (const float*)d_in[5];
  const float* pb   = (const float*)d_in[6];
  int* out = (int*)d_out;

  char* ws = (char*)d_ws;
  unsigned long long* winners = (unsigned long long*)(ws + 0);
  unsigned int* cntA = (unsigned int*)(ws + 32768);
  unsigned int* cntB = (unsigned int*)(ws + 40960);
  float* xT   = (float*)(ws + 49152);
  float* hb0  = (float*)(ws + 147456);
  float* hb1  = (float*)(ws + 278528);
  float* cT   = (float*)(ws + 409600);
  float* zpart = (float*)(ws + 540672);

  k_init<<<377, 256, 0, stream>>>(img, emb, xT, hb0, cT, winners, cntA, cntB);

  // Host-side key chain (pure, identical every call -> graph-capture safe).
  uint32_t k0 = 0u, k1 = 42u;  // jax.random.key(42) -> [0, 42]
  for (int t = 0; t < STEPS; ++t) {
    uint32_t n0, n1, su0, su1;
    tf2x32(k0, k1, 0u, 0u, n0, n1);   // split row 0 -> new key
    tf2x32(k0, k1, 0u, 1u, su0, su1); // split row 1 -> subkey
    k0 = n0; k1 = n1;

    const float* hrd = (t & 1) ? hb1 : hb0;
    float* hwr = (t & 1) ? hb0 : hb1;
    k_lstm<<<512, 512, 0, stream>>>(Km, Rm, bias, xT, hrd, hwr, cT, zpart,
                                    cntA, t);
    k_logits<<<500, 512, 0, stream>>>(Pw, pb, emb, hwr, xT, winners, cntB,
                                      out, t, su0, su1);
  }
}